// Round 9
// baseline (172.400 us; speedup 1.0000x reference)
//
#include <hip/hip_runtime.h>
#include <cstdint>
#include <cmath>

#define NROWS 8192
#define KDIM  512            // elements; also bytes/row in fp8

typedef int    i32x4  __attribute__((ext_vector_type(4)));
typedef int    i32x8  __attribute__((ext_vector_type(8)));
typedef float  f32x16 __attribute__((ext_vector_type(16)));
typedef unsigned char u8;

#define AS1(p) ((const __attribute__((address_space(1))) void*)(p))
#define AS3(p) ((__attribute__((address_space(3))) void*)(p))

// --- Kernel 1: row L2-normalize fp32 -> fp8 e4m3 (OCP, HW cvt), one wave/row.
// zi rows [0,8192), zj rows [8192,16384). Also zeroes the 128 accumulator slots.
__global__ __launch_bounds__(256) void nrm_kernel(const float* __restrict__ zi,
                                                  const float* __restrict__ zj,
                                                  u8* __restrict__ out,
                                                  double* __restrict__ acc) {
    if (blockIdx.x == 0 && threadIdx.x < 128) acc[threadIdx.x] = 0.0;
    const int wave = threadIdx.x >> 6;
    const int lane = threadIdx.x & 63;
    const int row  = blockIdx.x * 4 + wave;            // 0..16383
    const float* src = (row < NROWS) ? zi + (size_t)row * KDIM
                                     : zj + (size_t)(row - NROWS) * KDIM;
    float4 a = ((const float4*)src)[lane];
    float4 b = ((const float4*)src)[lane + 64];
    float ss = a.x*a.x + a.y*a.y + a.z*a.z + a.w*a.w
             + b.x*b.x + b.y*b.y + b.z*b.z + b.w*b.w;
    #pragma unroll
    for (int off = 32; off >= 1; off >>= 1) ss += __shfl_xor(ss, off, 64);
    const float inv = 1.0f / fmaxf(sqrtf(ss), 1e-12f);
    int p0 = 0, p1 = 0;
    p0 = __builtin_amdgcn_cvt_pk_fp8_f32(a.x * inv, a.y * inv, p0, false);
    p0 = __builtin_amdgcn_cvt_pk_fp8_f32(a.z * inv, a.w * inv, p0, true);
    p1 = __builtin_amdgcn_cvt_pk_fp8_f32(b.x * inv, b.y * inv, p1, false);
    p1 = __builtin_amdgcn_cvt_pk_fp8_f32(b.z * inv, b.w * inv, p1, true);
    int* dst = (int*)(out + (size_t)row * KDIM);
    dst[lane]      = p0;
    dst[lane + 64] = p1;
}

// --- Kernel 2: fused MX-fp8 A*B^T -> exp(10*dot) -> global sum.
// R20: faithful m201-class 8-phase PHASE-LOCKED schedule at 256x256 / 8 waves.
// Evidence trail: MFMA-busy is a constant ~21 us (ideal work) in R11-R19 while
// the wall varies 82-106 with structure, NOT with occupancy (R19: 12 waves/CU
// = slower) and NOT with load latency (R15 counted-vmcnt null). Our 25%
// MfmaUtil == the guide's measured 2-phase structural cap (m230). The one
// documented escape is the m201 template (62% MfmaUtil): phase-locked barrier
// pairs so the LDS port and the MFMA pipe each run full-rate BURSTS instead of
// colliding, with staging loads in flight across all of it. R16 failed this
// because of the known-fatal deviations (sched_barrier(0) order-pinning =
// m141's -42% trap + asm lgkmcnt inside phases); R20 removes exactly those:
//   * per K-tile(64B): vmcnt(4)+barrier  ->  [read bfr,af0,af1 || stage-A(t+2)]
//     barrier -> setprio1, 4 MFMA, setprio0 -> [read af2,af3 || stage-B(t+2)]
//     barrier -> setprio1, 4 MFMA, setprio0.  NO sched_barrier, NO asm lgkm:
//     the compiler keeps its fine-grained lgkmcnt scheduling (m97 evidence).
//   * 3 distinct named buffers (alias-clean, R13/R15-proven), stage distance 2:
//     tile t reads buf t%3, stages t+2 into (t+2)%3 (last read at t-1; its
//     readers passed this tile's top barrier). vmcnt(4) at each tile top =
//     stage(t) complete, stage(t+1)'s 4 loads stay in flight ACROSS barriers;
//     drains to 0 only at t=7.
//   * wave tile 128x64 (2Mx4N), accf[4][2]; staging/fragment/epilogue formulas
//     byte-identical to R16 (verified absmax 0 there).
// LDS 3 x 32 KB = 96 KB, 1 block/CU; ~216 regs -> 2 waves/SIMD.
// Triangle (R16-verified, square grid): pos = bx<32, skip bx<by, diag bx==by
// skips rr==cc, bx>by weight 2. XCD band remap (R18, neutral-to-mild-plus).
// Separate finalize kernel (R12/R13: in-kernel agent-acquire = L2 invalidate
// = 2x poison; R19's fence-free fused ticket saved nothing — keep it simple).
__global__ __launch_bounds__(512, 1) void gemm_exp_reduce(const u8* __restrict__ A,
                                                          const u8* __restrict__ B,
                                                          double* __restrict__ acc) {
    // XCD-band remap (bijective on 2048): xcd = bid&7 owns bx === xcd (mod 8).
    const int bid = blockIdx.x + 64 * blockIdx.y;
    const int bx  = (bid & 7) + 8 * ((bid >> 3) & 7);    // 0..63
    const int by  = bid >> 6;                            // 0..31
    const bool pos = (bx < 32);
    if (pos && bx < by) return;      // strict lower-tri pos block: mirror elsewhere

    __shared__ u8 lA0[256 * 64];     // 16 KB each (8 regions of 32r x 64B)
    __shared__ u8 lA1[256 * 64];
    __shared__ u8 lA2[256 * 64];
    __shared__ u8 lB0[256 * 64];
    __shared__ u8 lB1[256 * 64];
    __shared__ u8 lB2[256 * 64];
    __shared__ float red[8];

    const int tid  = threadIdx.x;
    const int lane = tid & 63;
    const int wave = tid >> 6;                 // 0..7
    const int m0   = by * 256;
    const int n0   = bx * 256;
    const int wm   = (wave >> 2) * 128;        // 2 M-groups
    const int wn   = (wave & 3) * 64;          // 4 N-groups

    f32x16 accf[4][2];
    #pragma unroll
    for (int i = 0; i < 4; ++i)
        #pragma unroll
        for (int j = 0; j < 2; ++j)
            #pragma unroll
            for (int r = 0; r < 16; ++r)
                accf[i][j][r] = 0.f;

    // staging (R16-verified): wave w stages region w (rows 32w..32w+31) of
    // BOTH A and B: 2 chunks of 16 rows x 1024 B -> 2+2 loads/thread/K-tile.
    const int bsw = (lane & 3) ^ ((lane >> 3) & 3);
    const u8* gA0 = A + (size_t)(m0 + wave * 32 + (lane >> 2)) * KDIM + bsw * 16;
    const u8* gB0 = B + (size_t)(n0 + wave * 32 + (lane >> 2)) * KDIM + bsw * 16;
    const int ldsO = wave * 2048 + lane * 16;

    auto stageA = [&](int t, u8 (&dA)[256 * 64]) {
        const size_t kb = (size_t)t * 64;
        #pragma unroll
        for (int c = 0; c < 2; ++c)
            __builtin_amdgcn_global_load_lds(AS1(gA0 + kb + (size_t)c * 16 * KDIM),
                                             AS3(&dA[ldsO + c * 1024]), 16, 0, 0);
    };
    auto stageB = [&](int t, u8 (&dB)[256 * 64]) {
        const size_t kb = (size_t)t * 64;
        #pragma unroll
        for (int c = 0; c < 2; ++c)
            __builtin_amdgcn_global_load_lds(AS1(gB0 + kb + (size_t)c * 16 * KDIM),
                                             AS3(&dB[ldsO + c * 1024]), 16, 0, 0);
    };

    // fragment read (R16-verified): lane row r=lane&31, k-half q=lane>>5;
    // swizzled slot p = r*4 + ((2q) ^ ((r>>1)&3)); partner chunk at ^16.
    const int r_  = lane & 31;
    const int q_  = lane >> 5;
    const int p16 = (r_ * 4 + ((2 * q_) ^ ((r_ >> 1) & 3))) * 16;
    const int aT0 = (wave >> 2) * 4;   // A regions aT0..aT0+3 (128 rows)
    const int bT0 = (wave & 3) * 2;    // B regions bT0..bT0+1 (64 rows)

    auto rdA = [&](const u8 (&sA)[256 * 64], int mi, i32x8& v) {
        const int off = (aT0 + mi) * 2048 + p16;
        *(i32x4*)&v       = *(const i32x4*)&sA[off];
        *((i32x4*)&v + 1) = *(const i32x4*)&sA[off ^ 16];
    };
    auto rdB = [&](const u8 (&sB)[256 * 64], int ni, i32x8& v) {
        const int off = (bT0 + ni) * 2048 + p16;
        *(i32x4*)&v       = *(const i32x4*)&sB[off];
        *((i32x4*)&v + 1) = *(const i32x4*)&sB[off ^ 16];
    };

    auto mm = [&](const i32x8& a, const i32x8 (&bfr)[2], f32x16 (&ac)[2]) {
        #pragma unroll
        for (int ni = 0; ni < 2; ++ni)
            ac[ni] = __builtin_amdgcn_mfma_scale_f32_32x32x64_f8f6f4(
                a, bfr[ni], ac[ni],
                0, 0,                 // cbsz=fp8(e4m3), blgp=fp8(e4m3)
                0, 0x7f7f7f7f,        // scale_a: every byte = 2^0
                0, 0x7f7f7f7f);       // scale_b
    };

    stageA(0, lA0); stageB(0, lB0);    // 4 loads in flight
    stageA(1, lA1); stageB(1, lB1);    // 8 in flight

    // Per K-tile: top vmcnt(4)+barrier (tile t ready; t+1's loads stay in
    // flight ACROSS barriers), then two phase-locked {reads||stage, barrier,
    // prio-MFMA-cluster} pairs. No sched_barrier, no asm lgkm (m141/m97).
#define GSTEP(RA, RB, TS, SA, SB, VM)                                  \
    {                                                                  \
        asm volatile("s_waitcnt vmcnt(" #VM ")" ::: "memory");         \
        __builtin_amdgcn_s_barrier();                                  \
        i32x8 af0, af1, af2, af3; i32x8 bfr[2];                        \
        rdB(RB, 0, bfr[0]); rdB(RB, 1, bfr[1]);                        \
        rdA(RA, 0, af0); rdA(RA, 1, af1);                              \
        if ((TS) >= 0) stageA((TS), SA);                               \
        __builtin_amdgcn_s_barrier();                                  \
        __builtin_amdgcn_s_setprio(1);                                 \
        mm(af0, bfr, accf[0]); mm(af1, bfr, accf[1]);                  \
        __builtin_amdgcn_s_setprio(0);                                 \
        rdA(RA, 2, af2); rdA(RA, 3, af3);                              \
        if ((TS) >= 0) stageB((TS), SB);                               \
        __builtin_amdgcn_s_barrier();                                  \
        __builtin_amdgcn_s_setprio(1);                                 \
        mm(af2, bfr, accf[2]); mm(af3, bfr, accf[3]);                  \
        __builtin_amdgcn_s_setprio(0);                                 \
    }

    GSTEP(lA0, lB0,  2, lA2, lB2, 4)   // t=0
    GSTEP(lA1, lB1,  3, lA0, lB0, 4)   // t=1
    GSTEP(lA2, lB2,  4, lA1, lB1, 4)   // t=2
    GSTEP(lA0, lB0,  5, lA2, lB2, 4)   // t=3
    GSTEP(lA1, lB1,  6, lA0, lB0, 4)   // t=4
    GSTEP(lA2, lB2,  7, lA1, lB1, 4)   // t=5
    GSTEP(lA0, lB0, -1, lA1, lB1, 4)   // t=6: tile7 still in flight
    GSTEP(lA1, lB1, -1, lA1, lB1, 0)   // t=7: final drain
#undef GSTEP

    // epilogue: exp(10*d) = exp2(d*10/ln2); diagonal pos block skips rr==cc
    const float LOG2E10 = 14.4269504088896341f;
    float part = 0.f;
    if (pos && bx == by) {
        #pragma unroll
        for (int mi = 0; mi < 4; ++mi)
            #pragma unroll
            for (int ni = 0; ni < 2; ++ni)
                #pragma unroll
                for (int r = 0; r < 16; ++r) {
                    // C/D 32x32: col=lane&31, row=(r&3)+8*(r>>2)+4*(lane>>5)
                    int rr = m0 + wm + mi * 32 + ((r & 3) + 8 * (r >> 2) + 4 * q_);
                    int cc = n0 + wn + ni * 32 + r_;
                    if (rr != cc) part += exp2f(accf[mi][ni][r] * LOG2E10);
                }
    } else {
        #pragma unroll
        for (int mi = 0; mi < 4; ++mi)
            #pragma unroll
            for (int ni = 0; ni < 2; ++ni)
                #pragma unroll
                for (int r = 0; r < 16; ++r)
                    part += exp2f(accf[mi][ni][r] * LOG2E10);
    }

    #pragma unroll
    for (int off = 32; off >= 1; off >>= 1) part += __shfl_xor(part, off, 64);
    if (lane == 0) red[wave] = part;
    __syncthreads();
    if (tid == 0) {
        double s = 0.0;
        #pragma unroll
        for (int w = 0; w < 8; ++w) s += (double)red[w];
        if (pos && bx > by) s *= 2.0;    // stands in for its skipped mirror
        atomicAdd(&acc[(pos ? 0 : 64) + (((unsigned)bx * 7 + (unsigned)by) & 63)], s);
    }
}

// --- Kernel 3: loss = log1p(neg/pos), pos += exact diagonal 8192*e^10.
// 128 threads, one global load each; LDS reduce then scalar finish.
__global__ __launch_bounds__(128) void finalize(const double* __restrict__ acc,
                                                float* __restrict__ out) {
    __shared__ double sp[128];
    const int t = threadIdx.x;
    sp[t] = acc[t];
    __syncthreads();
    if (t == 0) {
        double p = 0.0, n = 0.0;
        #pragma unroll
        for (int i = 0; i < 64; ++i) { p += sp[i]; n += sp[64 + i]; }
        p += 8192.0 * exp(10.0);
        out[0] = (float)log1p(n / p);
    }
}

extern "C" void kernel_launch(void* const* d_in, const int* in_sizes, int n_in,
                              void* d_out, int out_size, void* d_ws, size_t ws_size,
                              hipStream_t stream) {
    const float* zi = (const float*)d_in[0];
    const float* zj = (const float*)d_in[1];
    u8* nrm = (u8*)d_ws;                                      // [16384][512] fp8 = 8 MB
    double* acc = (double*)((char*)d_ws + (size_t)16384 * 512);

    nrm_kernel<<<4096, 256, 0, stream>>>(zi, zj, nrm, acc);
    dim3 grid(64, 32);   // x: 16384/256 n-tiles, y: 8192/256 m-tiles
    gemm_exp_reduce<<<grid, 512, 0, stream>>>(nrm, nrm, acc);
    finalize<<<1, 128, 0, stream>>>(acc, (float*)d_out);
}

// Round 10
// 148.021 us; speedup vs baseline: 1.1647x; 1.1647x over previous
//
#include <hip/hip_runtime.h>
#include <cstdint>
#include <cmath>

#define NROWS 8192
#define KDIM  512            // elements; also bytes/row in fp8

typedef int    i32x4  __attribute__((ext_vector_type(4)));
typedef int    i32x8  __attribute__((ext_vector_type(8)));
typedef float  f32x16 __attribute__((ext_vector_type(16)));
typedef unsigned char u8;

#define AS1(p) ((const __attribute__((address_space(1))) void*)(p))
#define AS3(p) ((__attribute__((address_space(3))) void*)(p))

// --- Kernel 1: row L2-normalize fp32 -> fp8 e4m3 (OCP, HW cvt), one wave/row.
// zi rows [0,8192), zj rows [8192,16384). Also zeroes the 128 accumulator slots.
__global__ __launch_bounds__(256) void nrm_kernel(const float* __restrict__ zi,
                                                  const float* __restrict__ zj,
                                                  u8* __restrict__ out,
                                                  double* __restrict__ acc) {
    if (blockIdx.x == 0 && threadIdx.x < 128) acc[threadIdx.x] = 0.0;
    const int wave = threadIdx.x >> 6;
    const int lane = threadIdx.x & 63;
    const int row  = blockIdx.x * 4 + wave;            // 0..16383
    const float* src = (row < NROWS) ? zi + (size_t)row * KDIM
                                     : zj + (size_t)(row - NROWS) * KDIM;
    float4 a = ((const float4*)src)[lane];
    float4 b = ((const float4*)src)[lane + 64];
    float ss = a.x*a.x + a.y*a.y + a.z*a.z + a.w*a.w
             + b.x*b.x + b.y*b.y + b.z*b.z + b.w*b.w;
    #pragma unroll
    for (int off = 32; off >= 1; off >>= 1) ss += __shfl_xor(ss, off, 64);
    const float inv = 1.0f / fmaxf(sqrtf(ss), 1e-12f);
    int p0 = 0, p1 = 0;
    p0 = __builtin_amdgcn_cvt_pk_fp8_f32(a.x * inv, a.y * inv, p0, false);
    p0 = __builtin_amdgcn_cvt_pk_fp8_f32(a.z * inv, a.w * inv, p0, true);
    p1 = __builtin_amdgcn_cvt_pk_fp8_f32(b.x * inv, b.y * inv, p1, false);
    p1 = __builtin_amdgcn_cvt_pk_fp8_f32(b.z * inv, b.w * inv, p1, true);
    int* dst = (int*)(out + (size_t)row * KDIM);
    dst[lane]      = p0;
    dst[lane + 64] = p1;
}

// --- Kernel 2: fused MX-fp8 A*B^T -> exp(10*dot) -> global sum.
// R21 = R18 (best: R11 BK=128 single-buffer 2-barrier loop + XCD band remap,
// 82 us, absmax 0) + 3-BIT XOR SWIZZLE fixing the structural 4-way LDS bank
// conflict. Evidence: SQ_LDS_BANK_CONFLICT == exactly 4 cyc x every
// ds_read_b128 in EVERY geometry (4,767,744 = 4 x 1,191,936 reads here;
// 6,324,224 = 4 x 1,581,056 in R19) — schedule-invariant. Cause (analytic):
// in the 32r x 64B region, even rows start at bank 4*swz, odd at 16+4*swz;
// the 2-bit XOR (r>>1)&3 spreads 16 same-parity lanes over only 4 four-bank
// slots -> inherent 4-way. Fix: fold the row's high bits in:
//   slot(r,c) = c ^ S(r),  S(r) = ((r>>1)&3) ^ ((r>>3)&3)
// Verified on paper: every consecutive 8-lane group covers all 32 banks
// exactly once (r=0..7 -> starts 0,16,4,20,8,24,12,28; r=8..15 ->
// 4,20,0,16,12,28,8,24); the partner-chunk off^16 property still holds
// ((2q+1)^S = (2q^S)^1); staging inverse becomes chunk-parity-dependent:
//   bsw_c = (lane&3) ^ ((lane>>3)&3) ^ ((2*(c&1) + (lane>>5)) & 3)
// (round-tripped: row 5 chunk 2 -> S(5)=2 -> slot 0; staged by lane 20 with
// bsw0=2; reader p16(r=5,q=0) = slot 2 holds chunk 0, partner slot 3 chunk 1).
// This removes ~4.77M conflict cycles (~7.8 us of per-CU LDS-port time).
// Everything else byte-identical to R18. Lessons held: no fused finalize
// (R12/R13: agent-acquire = per-block L2 inv = 2x), no sched_barrier pins
// (m141), no runtime-indexed LDS buffers (R12), 2 blocks/CU is the best
// structure (R16/R19/R20: 1 blk = 102-106, 3 blk small-tile = 95).
__global__ __launch_bounds__(256, 2) void gemm_exp_reduce(const u8* __restrict__ A,
                                                          const u8* __restrict__ B,
                                                          double* __restrict__ acc) {
    // XCD-band remap: xcd = bid&7 owns bx ∈ {xcd, xcd+8, ..., xcd+120},
    // by-major order -> same-XCD concurrent blocks share the A-panel.
    const int bid = blockIdx.x + 128 * blockIdx.y;
    const int bx  = (bid & 7) + 8 * ((bid >> 3) & 15);
    const int by  = bid >> 7;
    const bool pos = (bx < 64);
    if (pos && bx < 2 * by) return;   // strict lower-tri pos block: mirror elsewhere

    __shared__ u8 lA[2][256 * 64];   // 2 k-halves x 16 KB (8 regions of 32r x 64B)
    __shared__ u8 lB[2][128 * 64];   // 2 k-halves x 8 KB  (4 regions)
    __shared__ float red[4];

    const int tid  = threadIdx.x;
    const int lane = tid & 63;
    const int wave = tid >> 6;
    const int m0   = by * 256;
    const int n0   = bx * 128;
    const int wm   = (wave >> 1) * 128;
    const int wn   = (wave & 1) * 64;

    f32x16 accf[4][2];
    #pragma unroll
    for (int i = 0; i < 4; ++i)
        #pragma unroll
        for (int j = 0; j < 2; ++j)
            #pragma unroll
            for (int r = 0; r < 16; ++r)
                accf[i][j][r] = 0.f;

    // staging: 16-row chunks of 1024 B per k-half; A: chunks wave*4..+3,
    // B: wave*2..+1. LDS dest is linear (slot = c*64+lane); the global column
    // fetched must be the swizzle-inverse for LDS row R = (c&1)*16 + (lane>>2):
    //   bsw_c = (lane&3) ^ ((lane>>3)&3) ^ ((2*(c&1) + (lane>>5)) & 3)
    const int lr5  = (lane >> 5) & 1;
    const int bsw0 = (lane & 3) ^ ((lane >> 3) & 3) ^ lr5;            // c even
    const int bsw1 = (lane & 3) ^ ((lane >> 3) & 3) ^ ((2 + lr5) & 3); // c odd
    const u8* gA0 = A + (size_t)(m0 + wave * 64 + (lane >> 2)) * KDIM;
    const u8* gB0 = B + (size_t)(n0 + wave * 32 + (lane >> 2)) * KDIM;
    const int ldsA = wave * 4096 + lane * 16;
    const int ldsB = wave * 2048 + lane * 16;

    // fragment read: lane row r=lane&31, k-half q=lane>>5 (chunks 2q,2q+1);
    // swizzled slot p = r*4 + ((2q) ^ S(r)), S(r)=((r>>1)&3)^((r>>3)&3);
    // partner chunk at ^16.
    const int r_  = lane & 31;
    const int q_  = lane >> 5;
    const int p16 = (r_ * 4 + ((2 * q_) ^ ((r_ >> 1) & 3) ^ ((r_ >> 3) & 3))) * 16;
    const int aT0 = (wave >> 1) * 4;   // A regions aT0..aT0+3 (128 rows)
    const int bT0 = (wave & 1) * 2;    // B regions bT0..bT0+1 (64 rows)

    for (int k0 = 0; k0 < KDIM; k0 += 128) {   // BK=128: 4 iters, 8 barriers total
        __syncthreads();   // previous iteration's ds_reads done before overwrite
        #pragma unroll
        for (int h = 0; h < 2; ++h) {
            const size_t kb = (size_t)k0 + h * 64;
            #pragma unroll
            for (int c = 0; c < 4; ++c) {
                const int bsw = (c & 1) ? bsw1 : bsw0;
                __builtin_amdgcn_global_load_lds(
                    AS1(gA0 + kb + (size_t)c * 16 * KDIM + bsw * 16),
                    AS3(&lA[h][ldsA + c * 1024]), 16, 0, 0);
            }
            #pragma unroll
            for (int c = 0; c < 2; ++c) {
                const int bsw = (c & 1) ? bsw1 : bsw0;
                __builtin_amdgcn_global_load_lds(
                    AS1(gB0 + kb + (size_t)c * 16 * KDIM + bsw * 16),
                    AS3(&lB[h][ldsB + c * 1024]), 16, 0, 0);
            }
        }
        __syncthreads();   // vmcnt drain + barrier: both k-halves ready

        #pragma unroll
        for (int h = 0; h < 2; ++h) {   // 16 MFMAs between barrier pairs
            i32x8 af[4], bfr[2];
            #pragma unroll
            for (int mi = 0; mi < 4; ++mi) {
                const int off = (aT0 + mi) * 2048 + p16;
                *(i32x4*)&af[mi]       = *(const i32x4*)&lA[h][off];
                *((i32x4*)&af[mi] + 1) = *(const i32x4*)&lA[h][off ^ 16];
            }
            #pragma unroll
            for (int ni = 0; ni < 2; ++ni) {
                const int off = (bT0 + ni) * 2048 + p16;
                *(i32x4*)&bfr[ni]       = *(const i32x4*)&lB[h][off];
                *((i32x4*)&bfr[ni] + 1) = *(const i32x4*)&lB[h][off ^ 16];
            }
            #pragma unroll
            for (int mi = 0; mi < 4; ++mi)
                #pragma unroll
                for (int ni = 0; ni < 2; ++ni)
                    accf[mi][ni] = __builtin_amdgcn_mfma_scale_f32_32x32x64_f8f6f4(
                        af[mi], bfr[ni], accf[mi][ni],
                        0, 0,                 // cbsz=fp8(e4m3), blgp=fp8(e4m3)
                        0, 0x7f7f7f7f,        // scale_a: every byte = 2^0
                        0, 0x7f7f7f7f);       // scale_b
        }
    }

    // epilogue: exp(10*d) = exp2(d*10/ln2); near-diag pos blocks skip rr==cc
    const float LOG2E10 = 14.4269504088896341f;
    float part = 0.f;
    if (pos && (bx >> 1) == by) {
        #pragma unroll
        for (int mi = 0; mi < 4; ++mi)
            #pragma unroll
            for (int ni = 0; ni < 2; ++ni)
                #pragma unroll
                for (int r = 0; r < 16; ++r) {
                    // C/D 32x32: col=lane&31, row=(r&3)+8*(r>>2)+4*(lane>>5)
                    int rr = m0 + wm + mi * 32 + ((r & 3) + 8 * (r >> 2) + 4 * q_);
                    int cc = n0 + wn + ni * 32 + r_;
                    if (rr != cc) part += exp2f(accf[mi][ni][r] * LOG2E10);
                }
    } else {
        #pragma unroll
        for (int mi = 0; mi < 4; ++mi)
            #pragma unroll
            for (int ni = 0; ni < 2; ++ni)
                #pragma unroll
                for (int r = 0; r < 16; ++r)
                    part += exp2f(accf[mi][ni][r] * LOG2E10);
    }

    #pragma unroll
    for (int off = 32; off >= 1; off >>= 1) part += __shfl_xor(part, off, 64);
    if (lane == 0) red[wave] = part;
    __syncthreads();
    if (tid == 0) {
        double s = (double)red[0] + (double)red[1] + (double)red[2] + (double)red[3];
        if (pos && bx >= 2 * by + 2) s *= 2.0;   // stands in for its skipped mirror
        atomicAdd(&acc[(pos ? 0 : 64) + (((unsigned)bx * 7 + (unsigned)by) & 63)], s);
    }
}

// --- Kernel 3: loss = log1p(neg/pos), pos += exact diagonal 8192*e^10.
// 128 threads, one global load each; LDS reduce then scalar finish.
__global__ __launch_bounds__(128) void finalize(const double* __restrict__ acc,
                                                float* __restrict__ out) {
    __shared__ double sp[128];
    const int t = threadIdx.x;
    sp[t] = acc[t];
    __syncthreads();
    if (t == 0) {
        double p = 0.0, n = 0.0;
        #pragma unroll
        for (int i = 0; i < 64; ++i) { p += sp[i]; n += sp[64 + i]; }
        p += 8192.0 * exp(10.0);
        out[0] = (float)log1p(n / p);
    }
}

extern "C" void kernel_launch(void* const* d_in, const int* in_sizes, int n_in,
                              void* d_out, int out_size, void* d_ws, size_t ws_size,
                              hipStream_t stream) {
    const float* zi = (const float*)d_in[0];
    const float* zj = (const float*)d_in[1];
    u8* nrm = (u8*)d_ws;                                      // [16384][512] fp8 = 8 MB
    double* acc = (double*)((char*)d_ws + (size_t)16384 * 512);

    nrm_kernel<<<4096, 256, 0, stream>>>(zi, zj, nrm, acc);
    dim3 grid(128, 32);   // x: 16384/128 n-tiles, y: 8192/256 m-tiles
    gemm_exp_reduce<<<grid, 256, 0, stream>>>(nrm, nrm, acc);
    finalize<<<1, 128, 0, stream>>>(acc, (float*)d_out);
}